// Round 10
// baseline (408.788 us; speedup 1.0000x reference)
//
#include <hip/hip_runtime.h>
#include <hip/hip_bf16.h>
#include <stdint.h>

// Problem: h_t = Lam @ h_{t-1} + B @ x_t ; BS=16, T=4096, D=256, fp32 in/out.
// Two-level chunked scan: level-1 chunks c=64, level-2 superchunks of 8.
// R12 (from R11's 367us, absmax 5.5):
//  gemm_wide: full-N GEMM (block = 64 rows x 256 cols) for the Bx GEMM and
//  the chunk-summary GEMM. R11's 4 n-tile blocks each re-read the same A
//  rows (FETCH 131MB vs 64MB ideal for step 2). One block now computes all
//  256 columns -> A fetched exactly once. Same per-output K order =>
//  bit-identical (absmax stays 5.5).

#define CHUNK  64

typedef short v8s __attribute__((ext_vector_type(8)));   // 8 x bf16 (4 VGPRs)
typedef float v4f __attribute__((ext_vector_type(4)));   // MFMA accum

static __device__ __forceinline__ unsigned short f2u(float f) {
  union { float f; unsigned int u; } x; x.f = f;
  unsigned int u = x.u + 0x7FFFu + ((x.u >> 16) & 1u);   // RNE f32->bf16
  return (unsigned short)(u >> 16);
}
static __device__ __forceinline__ float u2f(unsigned short h) {
  union { unsigned int u; float f; } x; x.u = ((unsigned int)h) << 16;
  return x.f;
}
// Workgroup barrier that only drains LDS (lgkmcnt), leaving vmcnt free-running
// so register prefetch loads survive across it.
static __device__ __forceinline__ void lds_barrier() {
  asm volatile("s_waitcnt lgkmcnt(0)\n\ts_barrier" ::: "memory");
}

// ---------------------------------------------------------------------------
// gemm_wide: block computes 64 rows x ALL 256 cols. A: f32 or bf16 [M,K]
// (lda). B: bf16 [K,256] (ldb). C: f32 (split-K partials) or bf16.
// grid = (M/64, ksplits). Depth-1 reg-prefetch staging as gemm_tile.
// Per-output K accumulation order identical to gemm_tile => bit-identical.
// ---------------------------------------------------------------------------
template<bool A_F32, bool C_BF16>
__global__ __launch_bounds__(256) void gemm_wide(
    const void* __restrict__ Ap, const unsigned short* __restrict__ Bp,
    void* __restrict__ Cp, int lda, int ldb, int ldc, int Kper, long csplit)
{
  __shared__ unsigned short As[64][72];    // [m][k]
  __shared__ unsigned short Bst[256][72];  // [n][k] transposed
  const int tid = threadIdx.x;
  const int lane = tid & 63, w = tid >> 6;       // 4 waves
  const int q = lane >> 4, ln = lane & 15;
  const long m0 = (long)blockIdx.x * 64;
  const int  kz = blockIdx.y;
  const long kbase = (long)kz * Kper;
  const int sm = tid >> 2;          // A staging row 0..63
  const int sk = (tid & 3) << 4;    // A staging col 0,16,32,48
  const int bk = tid >> 2;          // B staging k-row 0..63
  const int bn = (tid & 3) << 6;    // B staging n-chunk 0,64,128,192

  v4f acc[16];
#pragma unroll
  for (int i = 0; i < 16; ++i) acc[i] = 0;

  float4 fA[4];
  v8s aR0, aR1, bR[8];

  auto load_tile = [&](long kg) {
    if (A_F32) {
      const float* A = (const float*)Ap + (m0 + sm) * (long)lda + kg + sk;
#pragma unroll
      for (int t = 0; t < 4; ++t) fA[t] = ((const float4*)A)[t];
    } else {
      const unsigned short* A = (const unsigned short*)Ap + (m0 + sm) * (long)lda + kg + sk;
      aR0 = ((const v8s*)A)[0]; aR1 = ((const v8s*)A)[1];
    }
    const unsigned short* Bg = Bp + (kg + bk) * (long)ldb + bn;
#pragma unroll
    for (int t = 0; t < 8; ++t) bR[t] = ((const v8s*)Bg)[t];
  };

  load_tile(kbase);

  for (int ks = 0; ks < Kper; ks += 64) {
    __syncthreads();
    if (A_F32) {
      unsigned short* d = &As[sm][sk];
#pragma unroll
      for (int t = 0; t < 4; ++t) {
        d[4*t+0] = f2u(fA[t].x); d[4*t+1] = f2u(fA[t].y);
        d[4*t+2] = f2u(fA[t].z); d[4*t+3] = f2u(fA[t].w);
      }
    } else {
      *(v8s*)&As[sm][sk] = aR0; *(v8s*)&As[sm][sk + 8] = aR1;
    }
#pragma unroll
    for (int c = 0; c < 8; ++c)
#pragma unroll
      for (int r = 0; r < 8; ++r)
        Bst[bn + c*8 + r][bk] = (unsigned short)bR[c][r];
    __syncthreads();
    if (ks + 64 < Kper) load_tile(kbase + ks + 64);
#pragma unroll
    for (int kb = 0; kb < 64; kb += 32) {
      v8s a = *(const v8s*)&As[w*16 + ln][kb + q*8];
#pragma unroll
      for (int nb = 0; nb < 16; ++nb) {
        v8s b = *(const v8s*)&Bst[nb*16 + ln][kb + q*8];
        acc[nb] = __builtin_amdgcn_mfma_f32_16x16x32_bf16(a, b, acc[nb], 0, 0, 0);
      }
    }
  }
#pragma unroll
  for (int nb = 0; nb < 16; ++nb)
#pragma unroll
    for (int r = 0; r < 4; ++r) {
      const long row = m0 + w*16 + q*4 + r;
      const long col = nb*16 + ln;
      float v = acc[nb][r];
      if (C_BF16) ((unsigned short*)Cp)[row * (long)ldc + col] = f2u(v);
      else ((float*)Cp + (long)kz * csplit)[row * (long)ldc + col] = v;
    }
}

// ---------------------------------------------------------------------------
// Generic 64x64-tile bf16 MFMA GEMM, depth-1 software-pipelined staging.
// (kept for the small tail GEMMs: S2, Abf)
// ---------------------------------------------------------------------------
template<bool A_F32, bool C_BF16, bool ADD_C>
__global__ __launch_bounds__(256) void gemm_tile(
    const void* __restrict__ Ap, const unsigned short* __restrict__ Bp,
    void* __restrict__ Cp, int lda, int ldb, int ldc, int Kper, long csplit)
{
  __shared__ unsigned short As[64][72];
  __shared__ unsigned short Bst[64][72];
  const int tid = threadIdx.x;
  const int lane = tid & 63, w = tid >> 6;       // 4 waves
  const int q = lane >> 4, ln = lane & 15;
  const long n0 = (long)blockIdx.x * 64;
  const long m0 = (long)blockIdx.y * 64;
  const int  kz = blockIdx.z;
  const long kbase = (long)kz * Kper;
  const int sm = tid >> 2;
  const int sk = (tid & 3) << 4;

  v4f acc[4];
#pragma unroll
  for (int i = 0; i < 4; ++i) acc[i] = 0;

  float4 fA[4];
  v8s aR0, aR1, bR0, bR1;

  auto load_tile = [&](long kg) {
    if (A_F32) {
      const float* A = (const float*)Ap + (m0 + sm) * (long)lda + kg + sk;
#pragma unroll
      for (int t = 0; t < 4; ++t) fA[t] = ((const float4*)A)[t];
    } else {
      const unsigned short* A = (const unsigned short*)Ap + (m0 + sm) * (long)lda + kg + sk;
      aR0 = ((const v8s*)A)[0]; aR1 = ((const v8s*)A)[1];
    }
    const unsigned short* Bg = Bp + (kg + sm) * (long)ldb + n0 + sk;
    bR0 = ((const v8s*)Bg)[0]; bR1 = ((const v8s*)Bg)[1];
  };

  load_tile(kbase);

  for (int ks = 0; ks < Kper; ks += 64) {
    __syncthreads();
    if (A_F32) {
      unsigned short* d = &As[sm][sk];
#pragma unroll
      for (int t = 0; t < 4; ++t) {
        d[4*t+0] = f2u(fA[t].x); d[4*t+1] = f2u(fA[t].y);
        d[4*t+2] = f2u(fA[t].z); d[4*t+3] = f2u(fA[t].w);
      }
    } else {
      *(v8s*)&As[sm][sk] = aR0; *(v8s*)&As[sm][sk + 8] = aR1;
    }
#pragma unroll
    for (int r = 0; r < 8; ++r) Bst[sk + r][sm] = (unsigned short)bR0[r];
#pragma unroll
    for (int r = 0; r < 8; ++r) Bst[sk + 8 + r][sm] = (unsigned short)bR1[r];
    __syncthreads();
    if (ks + 64 < Kper) load_tile(kbase + ks + 64);
#pragma unroll
    for (int kb = 0; kb < 64; kb += 32) {
      v8s a = *(const v8s*)&As[w*16 + ln][kb + q*8];
#pragma unroll
      for (int nb = 0; nb < 4; ++nb) {
        v8s b = *(const v8s*)&Bst[nb*16 + ln][kb + q*8];
        acc[nb] = __builtin_amdgcn_mfma_f32_16x16x32_bf16(a, b, acc[nb], 0, 0, 0);
      }
    }
  }
#pragma unroll
  for (int nb = 0; nb < 4; ++nb)
#pragma unroll
    for (int r = 0; r < 4; ++r) {
      const long row = m0 + w*16 + q*4 + r;
      const long col = n0 + nb*16 + ln;
      float v = acc[nb][r];
      if (C_BF16) ((unsigned short*)Cp)[row * (long)ldc + col] = f2u(v);
      else {
        float* Cf = (float*)Cp + (long)kz * csplit;
        if (ADD_C) v += Cf[row * (long)ldc + col];
        Cf[row * (long)ldc + col] = v;
      }
    }
}

// ---------------------------------------------------------------------------
// Powers by doubling, split-bf16 (hi+lo): P_{mpow+jj} = P_mpow * P_jj.
// 512 threads, 128-wide K staging, 6 staged iters; bit-identical K order.
// Fused pack2 init at mpow==32.
// ---------------------------------------------------------------------------
__global__ __launch_bounds__(512) void pow_round(
    unsigned short* __restrict__ Phi, unsigned short* __restrict__ Plo, int mpow,
    unsigned short* __restrict__ Phi2, unsigned short* __restrict__ Plo2)
{
  __shared__ unsigned short As[64][136];
  __shared__ unsigned short Bst[64][136];
  const int tid = threadIdx.x, lane = tid & 63, w = tid >> 6;  // 8 waves
  const int q = lane >> 4, ln = lane & 15;
  const int jj = (blockIdx.x >> 2) + 1;
  const int n0 = (blockIdx.x & 3) * 64;
  const int m0 = blockIdx.y * 64;
  const int mb = w >> 1, nh = w & 1;
  const unsigned short* Ah = Phi + (size_t)mpow * 65536;
  const unsigned short* Al = Plo + (size_t)mpow * 65536;
  const unsigned short* Bh = Phi + (size_t)jj * 65536;
  const unsigned short* Bl = Plo + (size_t)jj * 65536;
  const int sm  = tid >> 3, sk  = (tid & 7) << 4;
  const int smk = tid >> 2, snk = (tid & 3) << 4;
  v4f acc[2];
#pragma unroll
  for (int i = 0; i < 2; ++i) acc[i] = 0;

  v8s aR0, aR1, bR0, bR1;
  auto load_tile = [&](int it) {
    const int seg = it >> 1, ks = (it & 1) << 7;
    const unsigned short* Asrc = (seg == 1) ? Al : Ah;
    const unsigned short* Bsrc = (seg == 2) ? Bl : Bh;
    const unsigned short* Ag = Asrc + (size_t)(m0 + sm) * 256 + ks + sk;
    aR0 = ((const v8s*)Ag)[0]; aR1 = ((const v8s*)Ag)[1];
    const unsigned short* Bg = Bsrc + (size_t)(ks + smk) * 256 + n0 + snk;
    bR0 = ((const v8s*)Bg)[0]; bR1 = ((const v8s*)Bg)[1];
  };

  load_tile(0);
  for (int it = 0; it < 6; ++it) {
    __syncthreads();
    *(v8s*)&As[sm][sk] = aR0; *(v8s*)&As[sm][sk + 8] = aR1;
#pragma unroll
    for (int r = 0; r < 8; ++r) Bst[snk + r][smk] = (unsigned short)bR0[r];
#pragma unroll
    for (int r = 0; r < 8; ++r) Bst[snk + 8 + r][smk] = (unsigned short)bR1[r];
    __syncthreads();
    if (it + 1 < 6) load_tile(it + 1);
#pragma unroll
    for (int kb = 0; kb < 128; kb += 32) {
      v8s a = *(const v8s*)&As[mb*16 + ln][kb + q*8];
#pragma unroll
      for (int nb = 0; nb < 2; ++nb) {
        v8s bb = *(const v8s*)&Bst[nh*32 + nb*16 + ln][kb + q*8];
        acc[nb] = __builtin_amdgcn_mfma_f32_16x16x32_bf16(a, bb, acc[nb], 0, 0, 0);
      }
    }
  }
  const size_t ob = (size_t)(mpow + jj) * 65536;
#pragma unroll
  for (int nb = 0; nb < 2; ++nb)
#pragma unroll
    for (int r = 0; r < 4; ++r) {
      const int row = m0 + mb*16 + q*4 + r;
      const int col = n0 + nh*32 + nb*16 + ln;
      float v = acc[nb][r];
      unsigned short hi = f2u(v);
      Phi[ob + (size_t)row*256 + col] = hi;
      Plo[ob + (size_t)row*256 + col] = f2u(v - u2f(hi));
      if (mpow == 32) {
        if (jj == 32) {
          Phi2[65536 + (size_t)row*256 + col] = hi;
          Plo2[65536 + (size_t)row*256 + col] = f2u(v - u2f(hi));
        } else if (jj == 1) {
          Phi2[(size_t)row*256 + col] = (row == col) ? (unsigned short)0x3F80 : (unsigned short)0;
          Plo2[(size_t)row*256 + col] = 0;
        }
      }
    }
}

// ---------------------------------------------------------------------------
// pack_init: Bt[e][d]=B[d][e], LamT[e][d]=Lam[d][e] (bf16); P_0=I, P_1=Lam hi/lo.
// ---------------------------------------------------------------------------
__global__ __launch_bounds__(256) void pack_init(
    const float* __restrict__ Bm, const float* __restrict__ Lam,
    unsigned short* __restrict__ Bt, unsigned short* __restrict__ LamT,
    unsigned short* __restrict__ Phi, unsigned short* __restrict__ Plo)
{
  const int idx = blockIdx.x * 256 + threadIdx.x;  // 0..65535
  const int e = idx >> 8, d = idx & 255;
  Bt[idx]   = f2u(Bm[d * 256 + e]);
  LamT[idx] = f2u(Lam[d * 256 + e]);
  float v = Lam[idx];                              // idx as (dd,ee) row-major
  unsigned short hi = f2u(v);
  Phi[65536 + idx] = hi;
  Plo[65536 + idx] = f2u(v - u2f(hi));
  const int dd = idx >> 8, ee = idx & 255;
  Phi[idx] = (dd == ee) ? (unsigned short)0x3F80 : (unsigned short)0;
  Plo[idx] = 0;
}

// ---------------------------------------------------------------------------
// pack_all: Ghat (blocks 0..1023) + Qcat/G2/LcT2 (blocks 1024..2335).
// ---------------------------------------------------------------------------
__global__ __launch_bounds__(256) void pack_all(
    const unsigned short* __restrict__ Phi,
    const unsigned short* __restrict__ Phi2, const unsigned short* __restrict__ Plo2,
    unsigned short* __restrict__ Ghat,
    unsigned short* __restrict__ Qcat, unsigned short* __restrict__ G2,
    unsigned short* __restrict__ LcT2hi, unsigned short* __restrict__ LcT2lo)
{
  __shared__ unsigned short tile[64][65];
  const int tx = threadIdx.x & 63, ty = threadIdx.x >> 6;  // ty 0..3
  const int blk0 = blockIdx.x;
  if (blk0 < 1024) {
    const int jpar = blk0 >> 4, t16 = blk0 & 15;
    const unsigned short* src = Phi + (size_t)(63 - jpar) * 65536;
    const int d0 = (t16 & 3) * 64, e0 = (t16 >> 2) * 64;
#pragma unroll
    for (int s = 0; s < 16; ++s)
      tile[ty*16 + s][tx] = src[(size_t)(d0 + ty*16 + s) * 256 + e0 + tx];
    __syncthreads();
#pragma unroll
    for (int s = 0; s < 16; ++s) {
      const int e = e0 + ty*16 + s, d = d0 + tx;
      Ghat[((size_t)(jpar*256 + e)) * 256 + d] = tile[tx][ty*16 + s];
    }
    return;
  }
  const int blk = blk0 - 1024;
  if (blk < 1152) {                                  // Qcat: 36x32 tiles of 64x64
    const int rt = blk >> 5, ct = blk & 31;
    const int k0 = rt * 64, c0 = ct * 64;
    const int r = c0 >> 8, d0 = c0 & 255;
    int p = 0, e0 = 0;
    bool zero = false;
    if (k0 < 256) { p = r; e0 = k0; }
    else {
      const int u = (k0 - 256) >> 8; e0 = (k0 - 256) & 255;
      if (u >= r) zero = true; else p = r - 1 - u;
    }
    if (zero) {
#pragma unroll
      for (int s = 0; s < 16; ++s)
        Qcat[(size_t)(k0 + ty*16 + s) * 2048 + c0 + tx] = 0;
      return;
    }
    const unsigned short* src = Phi2 + (size_t)p * 65536;
#pragma unroll
    for (int s = 0; s < 16; ++s)
      tile[ty*16 + s][tx] = src[(size_t)(d0 + ty*16 + s) * 256 + e0 + tx];
    __syncthreads();
#pragma unroll
    for (int s = 0; s < 16; ++s)
      Qcat[(size_t)(k0 + ty*16 + s) * 2048 + c0 + tx] = tile[tx][ty*16 + s];
  } else if (blk < 1280) {                           // G2: 32x4 tiles
    const int t = blk - 1152;
    const int rt = t >> 2, ct = t & 3;
    const int k0 = rt * 64, d0 = ct * 64;
    const int r = k0 >> 8, e0 = k0 & 255;
    const unsigned short* src = Phi2 + (size_t)(7 - r) * 65536;
#pragma unroll
    for (int s = 0; s < 16; ++s)
      tile[ty*16 + s][tx] = src[(size_t)(d0 + ty*16 + s) * 256 + e0 + tx];
    __syncthreads();
#pragma unroll
    for (int s = 0; s < 16; ++s)
      G2[(size_t)(k0 + ty*16 + s) * 256 + d0 + tx] = tile[tx][ty*16 + s];
  } else {                                           // LcT2 hi (16) + lo (16)
    const int t = blk - 1280;
    const int half = t >> 4, t16 = t & 15;
    const int d0 = (t16 & 3) * 64, e0 = (t16 >> 2) * 64;
    const unsigned short* src = (half ? Plo2 : Phi2) + (size_t)8 * 65536;
    unsigned short* dst = half ? LcT2lo : LcT2hi;
#pragma unroll
    for (int s = 0; s < 16; ++s)
      tile[ty*16 + s][tx] = src[(size_t)(d0 + ty*16 + s) * 256 + e0 + tx];
    __syncthreads();
#pragma unroll
    for (int s = 0; s < 16; ++s)
      dst[(size_t)(e0 + ty*16 + s) * 256 + d0 + tx] = tile[tx][ty*16 + s];
  }
}

// ---------------------------------------------------------------------------
// reduce split-K partials and scatter into Acat (bf16) S-region:
// s_{b, i=8m+u}[e] -> Acat[b*8+m][256 + u*256 + e]
// ---------------------------------------------------------------------------
__global__ __launch_bounds__(256) void reduce_s2(
    const float* __restrict__ Sp, unsigned short* __restrict__ Acat)
{
  const int f = blockIdx.x * 256 + threadIdx.x;   // 262144 total
  float v = 0;
#pragma unroll
  for (int z = 0; z < 8; ++z) v += Sp[(size_t)z * 262144 + f];
  const int e = f & 255, i = (f >> 8) & 63, b = f >> 14;
  const int u = i & 7, m = i >> 3;
  Acat[(size_t)(b*8 + m) * 2304 + 256 + u*256 + e] = f2u(v);
}

// ---------------------------------------------------------------------------
// Level-2 sequential combine: 8 steps, ONE workgroup, split-bf16 MFMA.
// ---------------------------------------------------------------------------
__global__ __launch_bounds__(512, 2) void k4b_combine(
    const unsigned short* __restrict__ LcT2hi, const unsigned short* __restrict__ LcT2lo,
    const float* __restrict__ S2, unsigned short* __restrict__ Acat)
{
  __shared__ unsigned short Hhi[16][264];
  __shared__ unsigned short Hlo[16][264];
  const int tid = threadIdx.x, lane = tid & 63, w = tid >> 6;  // 8 waves
  const int q = lane >> 4, ln = lane & 15;

  v8s bhi[8][2], blo[8][2];
#pragma unroll
  for (int kk = 0; kk < 8; ++kk)
#pragma unroll
    for (int nb = 0; nb < 2; ++nb) {
      const int n = 32*w + nb*16 + ln;
#pragma unroll
      for (int r = 0; r < 8; ++r) {
        const int k = kk*32 + q*8 + r;
        bhi[kk][nb][r] = (short)LcT2hi[k*256 + n];
        blo[kk][nb][r] = (short)LcT2lo[k*256 + n];
      }
    }
  for (int e = tid; e < 16*264; e += 512) { (&Hhi[0][0])[e] = 0; (&Hlo[0][0])[e] = 0; }
  lds_barrier();

  for (int m = 0; m < 8; ++m) {
    for (int e = tid; e < 4096; e += 512) {
      const int b = e >> 8, d = e & 255;
      Acat[(size_t)(b*8 + m) * 2304 + d] = Hhi[b][d];
    }
    v8s ahi[8], alo[8];
#pragma unroll
    for (int kk = 0; kk < 8; ++kk) {
      ahi[kk] = *(const v8s*)&Hhi[ln][kk*32 + q*8];
      alo[kk] = *(const v8s*)&Hlo[ln][kk*32 + q*8];
    }
    lds_barrier();
    v4f acc[2];
#pragma unroll
    for (int nb = 0; nb < 2; ++nb)
#pragma unroll
      for (int r = 0; r < 4; ++r) {
        const int bb = 4*q + r, col = 32*w + nb*16 + ln;
        acc[nb][r] = S2[(size_t)(bb*8 + m) * 256 + col];
      }
#pragma unroll
    for (int kk = 0; kk < 8; ++kk)
#pragma unroll
      for (int nb = 0; nb < 2; ++nb) {
        acc[nb] = __builtin_amdgcn_mfma_f32_16x16x32_bf16(ahi[kk], bhi[kk][nb], acc[nb], 0, 0, 0);
        acc[nb] = __builtin_amdgcn_mfma_f32_16x16x32_bf16(alo[kk], bhi[kk][nb], acc[nb], 0, 0, 0);
        acc[nb] = __builtin_amdgcn_mfma_f32_16x16x32_bf16(ahi[kk], blo[kk][nb], acc[nb], 0, 0, 0);
      }
#pragma unroll
    for (int nb = 0; nb < 2; ++nb)
#pragma unroll
      for (int r = 0; r < 4; ++r) {
        const int bb = 4*q + r, col = 32*w + nb*16 + ln;
        float v = acc[nb][r];
        unsigned short hi = f2u(v);
        Hhi[bb][col] = hi;
        Hlo[bb][col] = f2u(v - u2f(hi));
      }
    lds_barrier();
  }
}

// ---------------------------------------------------------------------------
// Final scan: state init from Abf (chunk-entry states, bf16); writes final h.
// Chunk c state in gs row 4c -> lane group q=c; epilogue on all 64 lanes.
// 256 blocks x 4 chunk-states, double-buffered gs, ONE lds_barrier/step.
// ---------------------------------------------------------------------------
__global__ __launch_bounds__(256, 1) void k5_scan(
    const unsigned short* __restrict__ LamT,
    const unsigned short* __restrict__ Bx,
    const unsigned short* __restrict__ Abf, float* __restrict__ Out)
{
  __shared__ unsigned short gs[2][16][264];
  const int tid = threadIdx.x, lane = tid & 63, w = tid >> 6;  // 4 waves
  const int q = lane >> 4, ln = lane & 15;
  const int blk = blockIdx.x;
  const int b  = blk >> 4;            // batch
  const int i0 = (blk * 4) & 63;      // first chunk index of this block

  v8s bf[8][4];                        // Lam^T frags, cols [64w,64w+64)
#pragma unroll
  for (int kk = 0; kk < 8; ++kk)
#pragma unroll
    for (int nb = 0; nb < 4; ++nb) {
      const int n = 64*w + nb*16 + ln;
#pragma unroll
      for (int r = 0; r < 8; ++r)
        bf[kk][nb][r] = (short)LamT[(kk*32 + q*8 + r) * 256 + n];
    }
  for (int e = tid; e < 2*16*264; e += 256) (&gs[0][0][0])[e] = 0;  // zero both bufs
  lds_barrier();
  // init rows {0,4,8,12} of buf 0 with chunk-entry states A_{b,i0+r}
#pragma unroll
  for (int r = 0; r < 4; ++r)
    gs[0][4*r][tid] = Abf[((size_t)(b*64 + i0 + r)) * 256 + tid];

  // this lane's chunk = q; its Bx/Out row base:
  const size_t baseq = ((size_t)b*4096 + (size_t)(i0 + q)*64) * 256;
  const int colw = 64*w;

  unsigned short bxr[2][4];            // depth-2 Bx prefetch ring (ALL lanes)
#pragma unroll
  for (int s = 0; s < 2; ++s)
#pragma unroll
    for (int nb = 0; nb < 4; ++nb)
      bxr[s][nb] = Bx[baseq + (size_t)s*256 + colw + nb*16 + ln];
  lds_barrier();

#pragma unroll 2
  for (int j = 0; j < CHUNK; ++j) {
    v8s a[8];
#pragma unroll
    for (int kk = 0; kk < 8; ++kk) a[kk] = *(const v8s*)&gs[j & 1][ln][kk*32 + q*8];
    v4f acc[4];
#pragma unroll
    for (int nb = 0; nb < 4; ++nb) acc[nb] = 0;
#pragma unroll
    for (int kk = 0; kk < 8; ++kk)
#pragma unroll
      for (int nb = 0; nb < 4; ++nb)
        acc[nb] = __builtin_amdgcn_mfma_f32_16x16x32_bf16(a[kk], bf[kk][nb], acc[nb], 0, 0, 0);
    // epilogue: lane group q owns chunk q = D row 4q = acc[nb][0]
    {
      const size_t rb = baseq + (size_t)j*256 + colw;
#pragma unroll
      for (int nb = 0; nb < 4; ++nb) {
        const float g = acc[nb][0] + u2f(bxr[j & 1][nb]);
        Out[rb + nb*16 + ln] = g;                          // FINAL h
        gs[(j + 1) & 1][4*q][colw + nb*16 + ln] = f2u(g);  // write OTHER buffer
      }
      if (j < CHUNK - 2) {
        const size_t rb2 = baseq + (size_t)(j + 2)*256 + colw;
#pragma unroll
        for (int nb = 0; nb < 4; ++nb)
          bxr[j & 1][nb] = Bx[rb2 + nb*16 + ln];
      }
    }
    lds_barrier();   // single barrier: new state visible to all waves
  }
}

// ---------------------------------------------------------------------------
extern "C" void kernel_launch(void* const* d_in, const int* in_sizes, int n_in,
                              void* d_out, int out_size, void* d_ws, size_t ws_size,
                              hipStream_t stream)
{
  const float* x   = (const float*)d_in[0];
  const float* Bm  = (const float*)d_in[1];
  const float* Lam = (const float*)d_in[2];
  float* Out = (float*)d_out;
  (void)in_sizes; (void)n_in; (void)out_size; (void)ws_size;

  char* ws = (char*)d_ws;
  size_t off = 0;
  auto alloc = [&](size_t bytes) { void* p = ws + off; off += (bytes + 255) & ~(size_t)255; return p; };
  unsigned short* Bx    = (unsigned short*)alloc((size_t)16777216 * 2);      // 32 MB
  unsigned short* Phi   = (unsigned short*)alloc((size_t)65 * 65536 * 2);    // 8.3 MB
  unsigned short* Plo   = (unsigned short*)alloc((size_t)65 * 65536 * 2);    // 8.3 MB
  unsigned short* Ghat  = (unsigned short*)alloc((size_t)16384 * 256 * 2);   // 8 MB
  unsigned short* Qcat  = (unsigned short*)alloc((size_t)2304 * 2048 * 2);   // 9.4 MB
  unsigned short* G2    = (unsigned short*)alloc((size_t)2048 * 256 * 2);    // 1 MB
  unsigned short* Phi2  = (unsigned short*)alloc((size_t)9 * 65536 * 2);
  unsigned short* Plo2  = (unsigned short*)alloc((size_t)9 * 65536 * 2);
  unsigned short* Bt    = (unsigned short*)alloc(131072);
  unsigned short* LamT  = (unsigned short*)alloc(131072);
  unsigned short* LcT2hi= (unsigned short*)alloc(131072);
  unsigned short* LcT2lo= (unsigned short*)alloc(131072);
  unsigned short* Acat  = (unsigned short*)alloc((size_t)128 * 2304 * 2);    // 0.6 MB
  float*          S2    = (float*)alloc(131072);
  unsigned short* Abf   = (unsigned short*)alloc(524288);
  float*          Spart = (float*)Plo;  // alias: Plo dead before summary GEMM writes Spart

  // 1) packs + P0/P1
  pack_init<<<dim3(256), dim3(256), 0, stream>>>(Bm, Lam, Bt, LamT, Phi, Plo);
  // 2) Bx = x @ B^T (bf16 out) — full-N blocks, A fetched once
  gemm_wide<true, true><<<dim3(1024, 1), dim3(256), 0, stream>>>(
      (const void*)x, Bt, (void*)Bx, 256, 256, 256, 256, 0);
  // 3) level-1 powers P_2..P_64 by doubling (mp=32 also seeds P2_0/P2_1)
  for (int mp = 1; mp <= 32; mp <<= 1)
    pow_round<<<dim3(mp * 4, 4, 1), dim3(512), 0, stream>>>(Phi, Plo, mp, Phi2, Plo2);
  // 4) level-2 powers P2_2..P2_8
  for (int mp = 1; mp <= 4; mp <<= 1)
    pow_round<<<dim3(mp * 4, 4, 1), dim3(512), 0, stream>>>(Phi2, Plo2, mp, Phi2, Plo2);
  // 5) pack GEMM operands (Ghat, Qcat, G2, LcT2)
  pack_all<<<dim3(2336), dim3(256), 0, stream>>>(Phi, Phi2, Plo2,
      Ghat, Qcat, G2, LcT2hi, LcT2lo);
  // 6) chunk summaries: S = Bx_r[1024,16384] @ Ghat (split-K=8, full-N blocks)
  gemm_wide<false, false><<<dim3(16, 8), dim3(256), 0, stream>>>(
      (const void*)Bx, Ghat, (void*)Spart, 16384, 256, 256, 2048, 262144);
  reduce_s2<<<dim3(1024), dim3(256), 0, stream>>>(Spart, Acat);
  // 7) level-2 summaries: S2[128,256] = Acat_S[128,2048] @ G2
  gemm_tile<false, false, false><<<dim3(4, 2, 1), dim3(256), 0, stream>>>(
      (const void*)(Acat + 256), G2, (void*)S2, 2304, 256, 256, 2048, 0);
  // 8) sequential combine over 8 superchunks -> A2 into Acat cols 0..255
  k4b_combine<<<dim3(1), dim3(512), 0, stream>>>(LcT2hi, LcT2lo, S2, Acat);
  // 9) all chunk-entry states: Abf[128,2048] = Acat[128,2304] @ Qcat
  gemm_tile<false, true, false><<<dim3(32, 2, 1), dim3(256), 0, stream>>>(
      (const void*)Acat, Qcat, (void*)Abf, 2304, 2048, 2048, 2304, 0);
  // 10) FINAL scan with chunk-entry init: Out = full h (no carry GEMM)
  k5_scan<<<dim3(256), dim3(256), 0, stream>>>(LamT, Bx, Abf, Out);
}

// Round 13
// 357.419 us; speedup vs baseline: 1.1437x; 1.1437x over previous
//
#include <hip/hip_runtime.h>
#include <hip/hip_bf16.h>
#include <stdint.h>

// Problem: h_t = Lam @ h_{t-1} + B @ x_t ; BS=16, T=4096, D=256, fp32 in/out.
// Two-level chunked scan: level-1 chunks c=64, level-2 superchunks of 8.
// R15 = R13/R14 third submission (two consecutive "container failed twice"
// infra errors; kernel audited: no hang vectors, no OOB, bijective swizzle;
// telemetry shows degrading infra — acquire 46->143s, pushes ~700s).
// Fallback if this fails again: revert to R11 source verbatim.
//  XCD-locality swizzle on the two fat GEMMs (steps 2 and 6): bijective
//  bid = c + 8*(4*g + n), mz = 8g + c puts the 4 n-tiles sharing an A-panel
//  on the SAME XCD, adjacent in dispatch order -> A fetched once per panel
//  into that XCD's L2 (was 4 misses). Pure index permutation, bit-exact.

#define CHUNK  64

typedef short v8s __attribute__((ext_vector_type(8)));   // 8 x bf16 (4 VGPRs)
typedef float v4f __attribute__((ext_vector_type(4)));   // MFMA accum

static __device__ __forceinline__ unsigned short f2u(float f) {
  union { float f; unsigned int u; } x; x.f = f;
  unsigned int u = x.u + 0x7FFFu + ((x.u >> 16) & 1u);   // RNE f32->bf16
  return (unsigned short)(u >> 16);
}
static __device__ __forceinline__ float u2f(unsigned short h) {
  union { unsigned int u; float f; } x; x.u = ((unsigned int)h) << 16;
  return x.f;
}
// Workgroup barrier that only drains LDS (lgkmcnt), leaving vmcnt free-running
// so register prefetch loads survive across it.
static __device__ __forceinline__ void lds_barrier() {
  asm volatile("s_waitcnt lgkmcnt(0)\n\ts_barrier" ::: "memory");
}

// ---------------------------------------------------------------------------
// Generic 64x64-tile bf16 MFMA GEMM, depth-1 software-pipelined staging.
// A: f32 or bf16 row-major [M,K] (lda). B: bf16 row-major [K,N] (ldb).
// C: f32 or bf16 [M,N] (ldc). ADD_C: C += A*B (f32 path).
// MT_SWZ == 0: 3D grid (n_tile, m_tile, k_split).
// MT_SWZ  > 0: 1D grid, XCD-locality swizzle. bid -> c=bid&7, s=bid>>3,
//   n=s&3, mz=((s>>2)<<3)|c, m=mz%MT_SWZ, kz=mz/MT_SWZ. The 4 n-tiles of
//   each (m,kz) A-panel are on one XCD, adjacent in dispatch order.
//   Requires (total mz count) % 8 == 0. Bit-exact work per block.
// ---------------------------------------------------------------------------
template<bool A_F32, bool C_BF16, bool ADD_C, int MT_SWZ>
__global__ __launch_bounds__(256) void gemm_tile(
    const void* __restrict__ Ap, const unsigned short* __restrict__ Bp,
    void* __restrict__ Cp, int lda, int ldb, int ldc, int Kper, long csplit)
{
  __shared__ unsigned short As[64][72];   // [m][k], pad to kill bank conflicts
  __shared__ unsigned short Bst[64][72];  // [n][k] (transposed for b128 frag reads)
  const int tid = threadIdx.x;
  const int lane = tid & 63, w = tid >> 6;       // 4 waves
  const int q = lane >> 4, ln = lane & 15;
  long n0, m0;
  int kz;
  if (MT_SWZ > 0) {
    const int bid = blockIdx.x;
    const int c = bid & 7, s = bid >> 3;
    const int n = s & 3;
    const int mz = ((s >> 2) << 3) | c;
    n0 = (long)n * 64;
    m0 = (long)(mz % MT_SWZ) * 64;
    kz = mz / MT_SWZ;
  } else {
    n0 = (long)blockIdx.x * 64;
    m0 = (long)blockIdx.y * 64;
    kz = blockIdx.z;
  }
  const long kbase = (long)kz * Kper;
  const int sm = tid >> 2;          // staging row 0..63
  const int sk = (tid & 3) << 4;    // staging col 0,16,32,48

  v4f acc[4];
#pragma unroll
  for (int i = 0; i < 4; ++i) acc[i] = 0;

  // staging registers (next K-tile in flight)
  float4 fA[4];
  v8s aR0, aR1, bR0, bR1;

  auto load_tile = [&](long kg) {
    if (A_F32) {
      const float* A = (const float*)Ap + (m0 + sm) * (long)lda + kg + sk;
#pragma unroll
      for (int t = 0; t < 4; ++t) fA[t] = ((const float4*)A)[t];
    } else {
      const unsigned short* A = (const unsigned short*)Ap + (m0 + sm) * (long)lda + kg + sk;
      aR0 = ((const v8s*)A)[0]; aR1 = ((const v8s*)A)[1];
    }
    const unsigned short* Bg = Bp + (kg + sm) * (long)ldb + n0 + sk;
    bR0 = ((const v8s*)Bg)[0]; bR1 = ((const v8s*)Bg)[1];
  };

  load_tile(kbase);                       // prologue: tile ks=0 in regs

  for (int ks = 0; ks < Kper; ks += 64) {
    __syncthreads();                      // prior MFMA phase done with LDS
    // write staged regs -> LDS
    if (A_F32) {
      unsigned short* d = &As[sm][sk];
#pragma unroll
      for (int t = 0; t < 4; ++t) {
        d[4*t+0] = f2u(fA[t].x); d[4*t+1] = f2u(fA[t].y);
        d[4*t+2] = f2u(fA[t].z); d[4*t+3] = f2u(fA[t].w);
      }
    } else {
      *(v8s*)&As[sm][sk] = aR0; *(v8s*)&As[sm][sk + 8] = aR1;
    }
#pragma unroll
    for (int r = 0; r < 8; ++r) Bst[sk + r][sm] = (unsigned short)bR0[r];
#pragma unroll
    for (int r = 0; r < 8; ++r) Bst[sk + 8 + r][sm] = (unsigned short)bR1[r];
    __syncthreads();
    // prefetch next tile into regs — overlaps with the MFMA phase below
    if (ks + 64 < Kper) load_tile(kbase + ks + 64);
#pragma unroll
    for (int kb = 0; kb < 64; kb += 32) {
      v8s a = *(const v8s*)&As[w*16 + ln][kb + q*8];
#pragma unroll
      for (int nb = 0; nb < 4; ++nb) {
        v8s b = *(const v8s*)&Bst[nb*16 + ln][kb + q*8];
        acc[nb] = __builtin_amdgcn_mfma_f32_16x16x32_bf16(a, b, acc[nb], 0, 0, 0);
      }
    }
  }
#pragma unroll
  for (int nb = 0; nb < 4; ++nb)
#pragma unroll
    for (int r = 0; r < 4; ++r) {
      const long row = m0 + w*16 + q*4 + r;        // D row = 4q+r within wave's 16
      const long col = n0 + nb*16 + ln;
      float v = acc[nb][r];
      if (C_BF16) ((unsigned short*)Cp)[row * (long)ldc + col] = f2u(v);
      else {
        float* Cf = (float*)Cp + (long)kz * csplit;
        if (ADD_C) v += Cf[row * (long)ldc + col];
        Cf[row * (long)ldc + col] = v;
      }
    }
}

// ---------------------------------------------------------------------------
// Powers by doubling, split-bf16 (hi+lo): P_{mpow+jj} = P_mpow * P_jj.
// 512 threads, 128-wide K staging, 6 staged iters; bit-identical K order.
// Fused pack2 init at mpow==32.
// ---------------------------------------------------------------------------
__global__ __launch_bounds__(512) void pow_round(
    unsigned short* __restrict__ Phi, unsigned short* __restrict__ Plo, int mpow,
    unsigned short* __restrict__ Phi2, unsigned short* __restrict__ Plo2)
{
  __shared__ unsigned short As[64][136];
  __shared__ unsigned short Bst[64][136];
  const int tid = threadIdx.x, lane = tid & 63, w = tid >> 6;  // 8 waves
  const int q = lane >> 4, ln = lane & 15;
  const int jj = (blockIdx.x >> 2) + 1;
  const int n0 = (blockIdx.x & 3) * 64;
  const int m0 = blockIdx.y * 64;
  const int mb = w >> 1, nh = w & 1;
  const unsigned short* Ah = Phi + (size_t)mpow * 65536;
  const unsigned short* Al = Plo + (size_t)mpow * 65536;
  const unsigned short* Bh = Phi + (size_t)jj * 65536;
  const unsigned short* Bl = Plo + (size_t)jj * 65536;
  const int sm  = tid >> 3, sk  = (tid & 7) << 4;
  const int smk = tid >> 2, snk = (tid & 3) << 4;
  v4f acc[2];
#pragma unroll
  for (int i = 0; i < 2; ++i) acc[i] = 0;

  v8s aR0, aR1, bR0, bR1;
  auto load_tile = [&](int it) {
    const int seg = it >> 1, ks = (it & 1) << 7;
    const unsigned short* Asrc = (seg == 1) ? Al : Ah;
    const unsigned short* Bsrc = (seg == 2) ? Bl : Bh;
    const unsigned short* Ag = Asrc + (size_t)(m0 + sm) * 256 + ks + sk;
    aR0 = ((const v8s*)Ag)[0]; aR1 = ((const v8s*)Ag)[1];
    const unsigned short* Bg = Bsrc + (size_t)(ks + smk) * 256 + n0 + snk;
    bR0 = ((const v8s*)Bg)[0]; bR1 = ((const v8s*)Bg)[1];
  };

  load_tile(0);
  for (int it = 0; it < 6; ++it) {
    __syncthreads();
    *(v8s*)&As[sm][sk] = aR0; *(v8s*)&As[sm][sk + 8] = aR1;
#pragma unroll
    for (int r = 0; r < 8; ++r) Bst[snk + r][smk] = (unsigned short)bR0[r];
#pragma unroll
    for (int r = 0; r < 8; ++r) Bst[snk + 8 + r][smk] = (unsigned short)bR1[r];
    __syncthreads();
    if (it + 1 < 6) load_tile(it + 1);
#pragma unroll
    for (int kb = 0; kb < 128; kb += 32) {
      v8s a = *(const v8s*)&As[mb*16 + ln][kb + q*8];
#pragma unroll
      for (int nb = 0; nb < 2; ++nb) {
        v8s bb = *(const v8s*)&Bst[nh*32 + nb*16 + ln][kb + q*8];
        acc[nb] = __builtin_amdgcn_mfma_f32_16x16x32_bf16(a, bb, acc[nb], 0, 0, 0);
      }
    }
  }
  const size_t ob = (size_t)(mpow + jj) * 65536;
#pragma unroll
  for (int nb = 0; nb < 2; ++nb)
#pragma unroll
    for (int r = 0; r < 4; ++r) {
      const int row = m0 + mb*16 + q*4 + r;
      const int col = n0 + nh*32 + nb*16 + ln;
      float v = acc[nb][r];
      unsigned short hi = f2u(v);
      Phi[ob + (size_t)row*256 + col] = hi;
      Plo[ob + (size_t)row*256 + col] = f2u(v - u2f(hi));
      if (mpow == 32) {
        if (jj == 32) {
          Phi2[65536 + (size_t)row*256 + col] = hi;
          Plo2[65536 + (size_t)row*256 + col] = f2u(v - u2f(hi));
        } else if (jj == 1) {
          Phi2[(size_t)row*256 + col] = (row == col) ? (unsigned short)0x3F80 : (unsigned short)0;
          Plo2[(size_t)row*256 + col] = 0;
        }
      }
    }
}

// ---------------------------------------------------------------------------
// pack_init: Bt[e][d]=B[d][e], LamT[e][d]=Lam[d][e] (bf16); P_0=I, P_1=Lam hi/lo.
// ---------------------------------------------------------------------------
__global__ __launch_bounds__(256) void pack_init(
    const float* __restrict__ Bm, const float* __restrict__ Lam,
    unsigned short* __restrict__ Bt, unsigned short* __restrict__ LamT,
    unsigned short* __restrict__ Phi, unsigned short* __restrict__ Plo)
{
  const int idx = blockIdx.x * 256 + threadIdx.x;  // 0..65535
  const int e = idx >> 8, d = idx & 255;
  Bt[idx]   = f2u(Bm[d * 256 + e]);
  LamT[idx] = f2u(Lam[d * 256 + e]);
  float v = Lam[idx];                              // idx as (dd,ee) row-major
  unsigned short hi = f2u(v);
  Phi[65536 + idx] = hi;
  Plo[65536 + idx] = f2u(v - u2f(hi));
  const int dd = idx >> 8, ee = idx & 255;
  Phi[idx] = (dd == ee) ? (unsigned short)0x3F80 : (unsigned short)0;
  Plo[idx] = 0;
}

// ---------------------------------------------------------------------------
// pack_all: Ghat (blocks 0..1023) + Qcat/G2/LcT2 (blocks 1024..2335).
// ---------------------------------------------------------------------------
__global__ __launch_bounds__(256) void pack_all(
    const unsigned short* __restrict__ Phi,
    const unsigned short* __restrict__ Phi2, const unsigned short* __restrict__ Plo2,
    unsigned short* __restrict__ Ghat,
    unsigned short* __restrict__ Qcat, unsigned short* __restrict__ G2,
    unsigned short* __restrict__ LcT2hi, unsigned short* __restrict__ LcT2lo)
{
  __shared__ unsigned short tile[64][65];
  const int tx = threadIdx.x & 63, ty = threadIdx.x >> 6;  // ty 0..3
  const int blk0 = blockIdx.x;
  if (blk0 < 1024) {
    const int jpar = blk0 >> 4, t16 = blk0 & 15;
    const unsigned short* src = Phi + (size_t)(63 - jpar) * 65536;
    const int d0 = (t16 & 3) * 64, e0 = (t16 >> 2) * 64;
#pragma unroll
    for (int s = 0; s < 16; ++s)
      tile[ty*16 + s][tx] = src[(size_t)(d0 + ty*16 + s) * 256 + e0 + tx];
    __syncthreads();
#pragma unroll
    for (int s = 0; s < 16; ++s) {
      const int e = e0 + ty*16 + s, d = d0 + tx;
      Ghat[((size_t)(jpar*256 + e)) * 256 + d] = tile[tx][ty*16 + s];
    }
    return;
  }
  const int blk = blk0 - 1024;
  if (blk < 1152) {                                  // Qcat: 36x32 tiles of 64x64
    const int rt = blk >> 5, ct = blk & 31;
    const int k0 = rt * 64, c0 = ct * 64;
    const int r = c0 >> 8, d0 = c0 & 255;
    int p = 0, e0 = 0;
    bool zero = false;
    if (k0 < 256) { p = r; e0 = k0; }
    else {
      const int u = (k0 - 256) >> 8; e0 = (k0 - 256) & 255;
      if (u >= r) zero = true; else p = r - 1 - u;
    }
    if (zero) {
#pragma unroll
      for (int s = 0; s < 16; ++s)
        Qcat[(size_t)(k0 + ty*16 + s) * 2048 + c0 + tx] = 0;
      return;
    }
    const unsigned short* src = Phi2 + (size_t)p * 65536;
#pragma unroll
    for (int s = 0; s < 16; ++s)
      tile[ty*16 + s][tx] = src[(size_t)(d0 + ty*16 + s) * 256 + e0 + tx];
    __syncthreads();
#pragma unroll
    for (int s = 0; s < 16; ++s)
      Qcat[(size_t)(k0 + ty*16 + s) * 2048 + c0 + tx] = tile[tx][ty*16 + s];
  } else if (blk < 1280) {                           // G2: 32x4 tiles
    const int t = blk - 1152;
    const int rt = t >> 2, ct = t & 3;
    const int k0 = rt * 64, d0 = ct * 64;
    const int r = k0 >> 8, e0 = k0 & 255;
    const unsigned short* src = Phi2 + (size_t)(7 - r) * 65536;
#pragma unroll
    for (int s = 0; s < 16; ++s)
      tile[ty*16 + s][tx] = src[(size_t)(d0 + ty*16 + s) * 256 + e0 + tx];
    __syncthreads();
#pragma unroll
    for (int s = 0; s < 16; ++s)
      G2[(size_t)(k0 + ty*16 + s) * 256 + d0 + tx] = tile[tx][ty*16 + s];
  } else {                                           // LcT2 hi (16) + lo (16)
    const int t = blk - 1280;
    const int half = t >> 4, t16 = t & 15;
    const int d0 = (t16 & 3) * 64, e0 = (t16 >> 2) * 64;
    const unsigned short* src = (half ? Plo2 : Phi2) + (size_t)8 * 65536;
    unsigned short* dst = half ? LcT2lo : LcT2hi;
#pragma unroll
    for (int s = 0; s < 16; ++s)
      tile[ty*16 + s][tx] = src[(size_t)(d0 + ty*16 + s) * 256 + e0 + tx];
    __syncthreads();
#pragma unroll
    for (int s = 0; s < 16; ++s)
      dst[(size_t)(e0 + ty*16 + s) * 256 + d0 + tx] = tile[tx][ty*16 + s];
  }
}

// ---------------------------------------------------------------------------
// reduce split-K partials and scatter into Acat (bf16) S-region:
// s_{b, i=8m+u}[e] -> Acat[b*8+m][256 + u*256 + e]
// ---------------------------------------------------------------------------
__global__ __launch_bounds__(256) void reduce_s2(
    const float* __restrict__ Sp, unsigned short* __restrict__ Acat)
{
  const int f = blockIdx.x * 256 + threadIdx.x;   // 262144 total
  float v = 0;
#pragma unroll
  for (int z = 0; z < 8; ++z) v += Sp[(size_t)z * 262144 + f];
  const int e = f & 255, i = (f >> 8) & 63, b = f >> 14;
  const int u = i & 7, m = i >> 3;
  Acat[(size_t)(b*8 + m) * 2304 + 256 + u*256 + e] = f2u(v);
}

// ---------------------------------------------------------------------------
// Level-2 sequential combine: 8 steps, ONE workgroup, split-bf16 MFMA.
// ---------------------------------------------------------------------------
__global__ __launch_bounds__(512, 2) void k4b_combine(
    const unsigned short* __restrict__ LcT2hi, const unsigned short* __restrict__ LcT2lo,
    const float* __restrict__ S2, unsigned short* __restrict__ Acat)
{
  __shared__ unsigned short Hhi[16][264];
  __shared__ unsigned short Hlo[16][264];
  const int tid = threadIdx.x, lane = tid & 63, w = tid >> 6;  // 8 waves
  const int q = lane >> 4, ln = lane & 15;

  v8s bhi[8][2], blo[8][2];
#pragma unroll
  for (int kk = 0; kk < 8; ++kk)
#pragma unroll
    for (int nb = 0; nb < 2; ++nb) {
      const int n = 32*w + nb*16 + ln;
#pragma unroll
      for (int r = 0; r < 8; ++r) {
        const int k = kk*32 + q*8 + r;
        bhi[kk][nb][r] = (short)LcT2hi[k*256 + n];
        blo[kk][nb][r] = (short)LcT2lo[k*256 + n];
      }
    }
  for (int e = tid; e < 16*264; e += 512) { (&Hhi[0][0])[e] = 0; (&Hlo[0][0])[e] = 0; }
  lds_barrier();

  for (int m = 0; m < 8; ++m) {
    for (int e = tid; e < 4096; e += 512) {
      const int b = e >> 8, d = e & 255;
      Acat[(size_t)(b*8 + m) * 2304 + d] = Hhi[b][d];
    }
    v8s ahi[8], alo[8];
#pragma unroll
    for (int kk = 0; kk < 8; ++kk) {
      ahi[kk] = *(const v8s*)&Hhi[ln][kk*32 + q*8];
      alo[kk] = *(const v8s*)&Hlo[ln][kk*32 + q*8];
    }
    lds_barrier();
    v4f acc[2];
#pragma unroll
    for (int nb = 0; nb < 2; ++nb)
#pragma unroll
      for (int r = 0; r < 4; ++r) {
        const int bb = 4*q + r, col = 32*w + nb*16 + ln;
        acc[nb][r] = S2[(size_t)(bb*8 + m) * 256 + col];
      }
#pragma unroll
    for (int kk = 0; kk < 8; ++kk)
#pragma unroll
      for (int nb = 0; nb < 2; ++nb) {
        acc[nb] = __builtin_amdgcn_mfma_f32_16x16x32_bf16(ahi[kk], bhi[kk][nb], acc[nb], 0, 0, 0);
        acc[nb] = __builtin_amdgcn_mfma_f32_16x16x32_bf16(alo[kk], bhi[kk][nb], acc[nb], 0, 0, 0);
        acc[nb] = __builtin_amdgcn_mfma_f32_16x16x32_bf16(ahi[kk], blo[kk][nb], acc[nb], 0, 0, 0);
      }
#pragma unroll
    for (int nb = 0; nb < 2; ++nb)
#pragma unroll
      for (int r = 0; r < 4; ++r) {
        const int bb = 4*q + r, col = 32*w + nb*16 + ln;
        float v = acc[nb][r];
        unsigned short hi = f2u(v);
        Hhi[bb][col] = hi;
        Hlo[bb][col] = f2u(v - u2f(hi));
      }
    lds_barrier();
  }
}

// ---------------------------------------------------------------------------
// Final scan: state init from Abf (chunk-entry states, bf16); writes final h.
// Chunk c state in gs row 4c -> lane group q=c; epilogue on all 64 lanes.
// 256 blocks x 4 chunk-states, double-buffered gs, ONE lds_barrier/step.
// ---------------------------------------------------------------------------
__global__ __launch_bounds__(256, 1) void k5_scan(
    const unsigned short* __restrict__ LamT,
    const unsigned short* __restrict__ Bx,
    const unsigned short* __restrict__ Abf, float* __restrict__ Out)
{
  __shared__ unsigned short gs[2][16][264];
  const int tid = threadIdx.x, lane = tid & 63, w = tid >> 6;  // 4 waves
  const int q = lane >> 4, ln = lane & 15;
  const int blk = blockIdx.x;
  const int b  = blk >> 4;            // batch
  const int i0 = (blk * 4) & 63;      // first chunk index of this block

  v8s bf[8][4];                        // Lam^T frags, cols [64w,64w+64)
#pragma unroll
  for (int kk = 0; kk < 8; ++kk)
#pragma unroll
    for (int nb = 0; nb < 4; ++nb) {
      const int n = 64*w + nb*16 + ln;
#pragma unroll
      for (int r = 0; r < 8; ++r)
        bf[kk][nb][r] = (short)LamT[(kk*32 + q*8 + r) * 256 + n];
    }
  for (int e = tid; e < 2*16*264; e += 256) (&gs[0][0][0])[e] = 0;  // zero both bufs
  lds_barrier();
  // init rows {0,4,8,12} of buf 0 with chunk-entry states A_{b,i0+r}
#pragma unroll
  for (int r = 0; r < 4; ++r)
    gs[0][4*r][tid] = Abf[((size_t)(b*64 + i0 + r)) * 256 + tid];

  // this lane's chunk = q; its Bx/Out row base:
  const size_t baseq = ((size_t)b*4096 + (size_t)(i0 + q)*64) * 256;
  const int colw = 64*w;

  unsigned short bxr[2][4];            // depth-2 Bx prefetch ring (ALL lanes)
#pragma unroll
  for (int s = 0; s < 2; ++s)
#pragma unroll
    for (int nb = 0; nb < 4; ++nb)
      bxr[s][nb] = Bx[baseq + (size_t)s*256 + colw + nb*16 + ln];
  lds_barrier();

#pragma unroll 2
  for (int j = 0; j < CHUNK; ++j) {
    v8s a[8];
#pragma unroll
    for (int kk = 0; kk < 8; ++kk) a[kk] = *(const v8s*)&gs[j & 1][ln][kk*32 + q*8];
    v4f acc[4];
#pragma unroll
    for (int nb = 0; nb < 4; ++nb) acc[nb] = 0;
#pragma unroll
    for (int kk = 0; kk < 8; ++kk)
#pragma unroll
      for (int nb = 0; nb < 4; ++nb)
        acc[nb] = __builtin_amdgcn_mfma_f32_16x16x32_bf16(a[kk], bf[kk][nb], acc[nb], 0, 0, 0);
    // epilogue: lane group q owns chunk q = D row 4q = acc[nb][0]
    {
      const size_t rb = baseq + (size_t)j*256 + colw;
#pragma unroll
      for (int nb = 0; nb < 4; ++nb) {
        const float g = acc[nb][0] + u2f(bxr[j & 1][nb]);
        Out[rb + nb*16 + ln] = g;                          // FINAL h
        gs[(j + 1) & 1][4*q][colw + nb*16 + ln] = f2u(g);  // write OTHER buffer
      }
      if (j < CHUNK - 2) {
        const size_t rb2 = baseq + (size_t)(j + 2)*256 + colw;
#pragma unroll
        for (int nb = 0; nb < 4; ++nb)
          bxr[j & 1][nb] = Bx[rb2 + nb*16 + ln];
      }
    }
    lds_barrier();   // single barrier: new state visible to all waves
  }
}

// ---------------------------------------------------------------------------
extern "C" void kernel_launch(void* const* d_in, const int* in_sizes, int n_in,
                              void* d_out, int out_size, void* d_ws, size_t ws_size,
                              hipStream_t stream)
{
  const float* x   = (const float*)d_in[0];
  const float* Bm  = (const float*)d_in[1];
  const float* Lam = (const float*)d_in[2];
  float* Out = (float*)d_out;
  (void)in_sizes; (void)n_in; (void)out_size; (void)ws_size;

  char* ws = (char*)d_ws;
  size_t off = 0;
  auto alloc = [&](size_t bytes) { void* p = ws + off; off += (bytes + 255) & ~(size_t)255; return p; };
  unsigned short* Bx    = (unsigned short*)alloc((size_t)16777216 * 2);      // 32 MB
  unsigned short* Phi   = (unsigned short*)alloc((size_t)65 * 65536 * 2);    // 8.3 MB
  unsigned short* Plo   = (unsigned short*)alloc((size_t)65 * 65536 * 2);    // 8.3 MB
  unsigned short* Ghat  = (unsigned short*)alloc((size_t)16384 * 256 * 2);   // 8 MB
  unsigned short* Qcat  = (unsigned short*)alloc((size_t)2304 * 2048 * 2);   // 9.4 MB
  unsigned short* G2    = (unsigned short*)alloc((size_t)2048 * 256 * 2);    // 1 MB
  unsigned short* Phi2  = (unsigned short*)alloc((size_t)9 * 65536 * 2);
  unsigned short* Plo2  = (unsigned short*)alloc((size_t)9 * 65536 * 2);
  unsigned short* Bt    = (unsigned short*)alloc(131072);
  unsigned short* LamT  = (unsigned short*)alloc(131072);
  unsigned short* LcT2hi= (unsigned short*)alloc(131072);
  unsigned short* LcT2lo= (unsigned short*)alloc(131072);
  unsigned short* Acat  = (unsigned short*)alloc((size_t)128 * 2304 * 2);    // 0.6 MB
  float*          S2    = (float*)alloc(131072);
  unsigned short* Abf   = (unsigned short*)alloc(524288);
  float*          Spart = (float*)Plo;  // alias: Plo dead before summary GEMM writes Spart

  // 1) packs + P0/P1
  pack_init<<<dim3(256), dim3(256), 0, stream>>>(Bm, Lam, Bt, LamT, Phi, Plo);
  // 2) Bx = x @ B^T (bf16 out) — XCD-swizzled: 4 n-tiles of each m-panel on
  //    one XCD, adjacent in dispatch order (A fetched once per panel).
  gemm_tile<true, true, false, 1024><<<dim3(4096), dim3(256), 0, stream>>>(
      (const void*)x, Bt, (void*)Bx, 256, 256, 256, 256, 0);
  // 3) level-1 powers P_2..P_64 by doubling (mp=32 also seeds P2_0/P2_1)
  for (int mp = 1; mp <= 32; mp <<= 1)
    pow_round<<<dim3(mp * 4, 4, 1), dim3(512), 0, stream>>>(Phi, Plo, mp, Phi2, Plo2);
  // 4) level-2 powers P2_2..P2_8
  for (int mp = 1; mp <= 4; mp <<= 1)
    pow_round<<<dim3(mp * 4, 4, 1), dim3(512), 0, stream>>>(Phi2, Plo2, mp, Phi2, Plo2);
  // 5) pack GEMM operands (Ghat, Qcat, G2, LcT2)
  pack_all<<<dim3(2336), dim3(256), 0, stream>>>(Phi, Phi2, Plo2,
      Ghat, Qcat, G2, LcT2hi, LcT2lo);
  // 6) chunk summaries: S = Bx_r[1024,16384] @ Ghat (split-K=8), XCD-swizzled
  //    (mz encodes m 0..15 + kz 0..7; 4 n-tiles per (m,kz) share one XCD).
  gemm_tile<false, false, false, 16><<<dim3(512), dim3(256), 0, stream>>>(
      (const void*)Bx, Ghat, (void*)Spart, 16384, 256, 256, 2048, 262144);
  reduce_s2<<<dim3(1024), dim3(256), 0, stream>>>(Spart, Acat);
  // 7) level-2 summaries: S2[128,256] = Acat_S[128,2048] @ G2
  gemm_tile<false, false, false, 0><<<dim3(4, 2, 1), dim3(256), 0, stream>>>(
      (const void*)(Acat + 256), G2, (void*)S2, 2304, 256, 256, 2048, 0);
  // 8) sequential combine over 8 superchunks -> A2 into Acat cols 0..255
  k4b_combine<<<dim3(1), dim3(512), 0, stream>>>(LcT2hi, LcT2lo, S2, Acat);
  // 9) all chunk-entry states: Abf[128,2048] = Acat[128,2304] @ Qcat
  gemm_tile<false, true, false, 0><<<dim3(32, 2, 1), dim3(256), 0, stream>>>(
      (const void*)Acat, Qcat, (void*)Abf, 2304, 2048, 2048, 2304, 0);
  // 10) FINAL scan with chunk-entry init: Out = full h (no carry GEMM)
  k5_scan<<<dim3(256), dim3(256), 0, stream>>>(LamT, Bx, Abf, Out);
}